// Round 8
// baseline (267.966 us; speedup 1.0000x reference)
//
#include <hip/hip_runtime.h>

typedef unsigned short u16;
typedef __bf16 bf8 __attribute__((ext_vector_type(8)));
typedef float f4 __attribute__((ext_vector_type(4)));

#define E_EDGES 32768
#define N_NODES 4096
// col layout of w (WNUM=6400): A[u<64][w<64] @0, B[u<64][w<16] @4096, C[u<16][w<16] @5120, D[u<16][w<64] @5376
// tile mt covers cols [mt*16,mt*16+16); group k4 = tiles 4k4..4k4+3; wave w owns tile 4k4+w.
// ranges in k4: A k4<64 (u=k4), B 64..79 (u=4(k4-64)+w), C 80..83 (u=4(k4-80)+w), D 84..99 (u=k4-84)
#define N0_CONST 0.1118033988749895f       // sqrt(1/80); also equals N1*INV_SQRT3
#define INV_SQRT3_CONST 0.5773502691896258f

__device__ __forceinline__ u16 f2bf(float f) {
    unsigned u = __float_as_uint(f);
    u += 0x7FFFu + ((u >> 16) & 1u);   // RNE
    return (u16)(u >> 16);
}

__device__ __forceinline__ void gld16(const u16* g, u16* l) {
    __builtin_amdgcn_global_load_lds((const __attribute__((address_space(1))) void*)g,
                                     (__attribute__((address_space(3))) void*)l, 16, 0, 0);
}

// Weight prep + src-degree histogram, one launch:
//  blocks 0..399:   w2s fragment-order swizzle (tile = 4KB contiguous)
//  blocks 400..415: w1t[c*128+k] = bf16(W1[k*128+c])
//  blocks 416..543: deg histogram over edge src (deg pre-zeroed by memsetAsync)
__global__ __launch_bounds__(256) void k_prep(const float* __restrict__ W2, const float* __restrict__ W1,
                                              const int* __restrict__ edge_index,
                                              u16* __restrict__ w2s, u16* __restrict__ w1t,
                                              int* __restrict__ deg) {
    int b = blockIdx.x;
    int tid = threadIdx.x;
    if (b < 400) {
        int ks = tid >> 6, l = tid & 63;
        int el = l & 15, q4 = l >> 4;
        int c = b * 16 + el;
        u16 tmp[8];
#pragma unroll
        for (int j = 0; j < 8; j++) {
            int k = ks * 32 + q4 * 8 + j;
            tmp[j] = f2bf(W2[(size_t)k * 6400 + c]);
        }
        *(uint4*)(w2s + b * 2048 + ks * 512 + l * 8) = *(uint4*)tmp;
    } else if (b < 416) {
        int t = (b - 400) * 256 + tid;
#pragma unroll
        for (int i = 0; i < 4; i++) {
            int idx = t * 4 + i;                // idx = c*128 + k
            int c = idx >> 7, k = idx & 127;
            w1t[idx] = f2bf(W1[k * 128 + c]);
        }
    } else {
        int t = (b - 416) * 256 + tid;          // 128 blocks * 256 = 32768 = E
        atomicAdd(&deg[edge_index[t]], 1);
    }
}

// Exclusive scan of deg[4096] -> ptr[0..4096] and cursor copy. 1 block, 64 threads.
__global__ void k_scan(const int* __restrict__ deg, int* __restrict__ ptr, int* __restrict__ cursor) {
    int t = threadIdx.x;           // 0..63
    int base = t * 64;
    int s = 0;
    for (int i = 0; i < 64; i++) s += deg[base + i];
    int x = s;
#pragma unroll
    for (int d = 1; d < 64; d <<= 1) {
        int y = __shfl_up(x, d, 64);
        if (t >= d) x += y;
    }
    int run = x - s;               // exclusive prefix
    for (int i = 0; i < 64; i++) {
        ptr[base + i] = run;
        cursor[base + i] = run;
        run += deg[base + i];
    }
    if (t == 63) ptr[4096] = run;
}

// h = relu(edge_attr @ W1 + b1), stored bf16 [E][128]; also fills CSR edge-id list via cursor
__global__ __launch_bounds__(256) void k_h(const float* __restrict__ ea,
                                           const u16* __restrict__ w1t,
                                           const float* __restrict__ b1,
                                           const int* __restrict__ edge_index,
                                           int* __restrict__ cursor,
                                           int* __restrict__ eids,
                                           u16* __restrict__ h) {
    __shared__ alignas(16) u16 ea_s[64][128];
    int tid = threadIdx.x;
    int e0 = blockIdx.x * 64;
    if (tid < 64) {                // CSR fill for this block's 64 edges
        int ge = e0 + tid;
        int s = edge_index[ge];
        int pos = atomicAdd(&cursor[s], 1);
        eids[pos] = ge;
    }
    {
        int e = tid >> 2, q = tid & 3;
        const float4* src = (const float4*)(ea + (size_t)(e0 + e) * 128 + q * 32);
#pragma unroll
        for (int i = 0; i < 8; i++) {
            float4 f = src[i];
            int c = q * 32 + i * 4;
            ea_s[e][c + 0] = f2bf(f.x); ea_s[e][c + 1] = f2bf(f.y);
            ea_s[e][c + 2] = f2bf(f.z); ea_s[e][c + 3] = f2bf(f.w);
        }
    }
    __syncthreads();
    int lane = tid & 63, wave = tid >> 6;
    int el = lane & 15, q4 = lane >> 4;
    f4 acc[4][2];
#pragma unroll
    for (int m = 0; m < 4; m++)
#pragma unroll
        for (int nt = 0; nt < 2; nt++) acc[m][nt] = (f4){0.f, 0.f, 0.f, 0.f};
#pragma unroll
    for (int ks = 0; ks < 4; ks++) {
        bf8 a[4], b[2];
#pragma unroll
        for (int m = 0; m < 4; m++) a[m] = *(const bf8*)&ea_s[m * 16 + el][ks * 32 + q4 * 8];
#pragma unroll
        for (int nt = 0; nt < 2; nt++) {
            int n = wave * 32 + nt * 16 + el;
            b[nt] = *(const bf8*)(w1t + n * 128 + ks * 32 + q4 * 8);
        }
#pragma unroll
        for (int m = 0; m < 4; m++)
#pragma unroll
            for (int nt = 0; nt < 2; nt++)
                acc[m][nt] = __builtin_amdgcn_mfma_f32_16x16x32_bf16(a[m], b[nt], acc[m][nt], 0, 0, 0);
    }
#pragma unroll
    for (int m = 0; m < 4; m++)
#pragma unroll
        for (int nt = 0; nt < 2; nt++) {
            int n = wave * 32 + nt * 16 + el;
            float bias = b1[n];
#pragma unroll
            for (int r = 0; r < 4; r++) {
                int e = e0 + m * 16 + q4 * 4 + r;
                float v = fmaxf(acc[m][nt][r] + bias, 0.f);
                h[(size_t)e * 128 + n] = f2bf(v);
            }
        }
}

// Fused: w = h@W2+b2 tile-by-tile -> contraction -> tp[E][112].
// Staged A double-buffer (global_load_lds, 4 tiles = 16KB per group, 1 barrier/group).
// Wave w consumes ONLY tile w of each group (ds_read 1x, not 4x); wave owns all 64 edges
// (hb[4][4] resident) and out0 cols [16w,16w+16). All contraction partials in registers.
__global__ __launch_bounds__(256, 2) void k_main(const u16* __restrict__ w2s,
                                                 const u16* __restrict__ hgl,
                                                 const float* __restrict__ b2,
                                                 const float* __restrict__ node_attr,
                                                 const int* __restrict__ edge_index,
                                                 const float* __restrict__ edge_sh,
                                                 float* __restrict__ tp) {
    __shared__ union {
        u16 h[64][128];                                        // 16 KB (prologue)
        u16 stage[2][8192];                                    // 32 KB (loop)
        struct { float accC[48][66]; float redB[16][66]; } ep; // 16.9 KB (epilogue)
    } ovl;
    __shared__ float sT[64][65];              // s[u][e]; epilogue: out0[e][c]
    __shared__ float vT[3][16][66];           // v[i][u][e]
    __shared__ float pT[16][66];              // INV_SQRT3*(v.sh1)[u][e]
    __shared__ float sh0_s[64];
    __shared__ float sh1_s[3][64];
    __shared__ int dst_s[64];

    int tid = threadIdx.x;
    int e0 = blockIdx.x * 64;

    // phase 1: edge meta
    if (tid < 64) {
        int ge = e0 + tid;
        dst_s[tid] = edge_index[E_EDGES + ge];
        float4 sh = *(const float4*)(edge_sh + (size_t)ge * 4);
        sh0_s[tid] = sh.x; sh1_s[0][tid] = sh.y; sh1_s[1][tid] = sh.z; sh1_s[2][tid] = sh.w;
    }
    __syncthreads();

    // phase 2: node features (transposed into LDS) + h tile into ovl.h
    {
        int e = tid >> 2, q = tid & 3;
        int dst = dst_s[e];
        const float* xp = node_attr + (size_t)dst * 112;
#pragma unroll
        for (int i = 0; i < 4; i++) {
            float4 f = *(const float4*)(xp + q * 16 + i * 4);
            int u = q * 16 + i * 4;
            sT[u + 0][e] = f.x; sT[u + 1][e] = f.y; sT[u + 2][e] = f.z; sT[u + 3][e] = f.w;
        }
        float vv[12];
#pragma unroll
        for (int i = 0; i < 3; i++) {
            float4 f = *(const float4*)(xp + 64 + q * 12 + i * 4);
            vv[i * 4 + 0] = f.x; vv[i * 4 + 1] = f.y; vv[i * 4 + 2] = f.z; vv[i * 4 + 3] = f.w;
        }
        float s1x = sh1_s[0][e], s1y = sh1_s[1][e], s1z = sh1_s[2][e];
#pragma unroll
        for (int u = 0; u < 4; u++) {
            float xa = vv[u * 3 + 0], xb = vv[u * 3 + 1], xc = vv[u * 3 + 2];
            int uu = q * 4 + u;
            vT[0][uu][e] = xa; vT[1][uu][e] = xb; vT[2][uu][e] = xc;
            pT[uu][e] = INV_SQRT3_CONST * (xa * s1x + xb * s1y + xc * s1z);
        }
        const uint4* hsrc = (const uint4*)(hgl + (size_t)(e0 + e) * 128) + q * 4;
        uint4* hdst = (uint4*)(&ovl.h[e][q * 32]);
#pragma unroll
        for (int i = 0; i < 4; i++) hdst[i] = hsrc[i];
    }
    __syncthreads();

    int lane = tid & 63, wave = tid >> 6;
    int el = lane & 15, q4 = lane >> 4;

    // B-fragments for all 64 edges (wave computes its m-tile across every edge)
    bf8 hb[4][4];
#pragma unroll
    for (int n = 0; n < 4; n++)
#pragma unroll
        for (int ks = 0; ks < 4; ks++)
            hb[n][ks] = *(const bf8*)&ovl.h[n * 16 + el][ks * 32 + q4 * 8];
    float sh0n[4];
#pragma unroll
    for (int n = 0; n < 4; n++) sh0n[n] = sh0_s[n * 16 + el];
    __syncthreads();   // h region free -> becomes stage buffers

    f4 acc0[4], accB[4], accC[3][4];
#pragma unroll
    for (int n = 0; n < 4; n++) { acc0[n] = (f4){0.f,0.f,0.f,0.f}; accB[n] = (f4){0.f,0.f,0.f,0.f}; }
#pragma unroll
    for (int i = 0; i < 3; i++)
#pragma unroll
        for (int n = 0; n < 4; n++) accC[i][n] = (f4){0.f,0.f,0.f,0.f};

    // preload group 0 -> buf0 (16 KB, 4 gld16/thread)
    {
        const u16* g = w2s + tid * 8;
#pragma unroll
        for (int c = 0; c < 4; c++) gld16(g + c * 2048, &ovl.stage[0][c * 2048 + tid * 8]);
    }
    float4 b2c = *(const float4*)(b2 + (size_t)wave * 16 + q4 * 4);

    for (int k4 = 0; k4 < 100; k4++) {
        __syncthreads();            // buf[k4&1] staged; prior group's reads done
        float4 b2n;
        if (k4 < 99) {              // prefetch group k4+1 -> other buffer
            const u16* g = w2s + (size_t)(k4 + 1) * 8192 + tid * 8;
            u16* l = &ovl.stage[(k4 + 1) & 1][tid * 8];
#pragma unroll
            for (int c = 0; c < 4; c++) gld16(g + c * 2048, l + c * 2048);
            b2n = *(const float4*)(b2 + (size_t)((k4 + 1) * 4 + wave) * 16 + q4 * 4);
        }
        // consume: wave reads ONLY its tile (4 ds_read_b128 = 4 KB)
        const u16* sp = &ovl.stage[k4 & 1][wave * 2048 + lane * 8];
        bf8 a0 = *(const bf8*)(sp);
        bf8 a1 = *(const bf8*)(sp + 512);
        bf8 a2 = *(const bf8*)(sp + 1024);
        bf8 a3 = *(const bf8*)(sp + 1536);
        f4 wf[4];
#pragma unroll
        for (int n = 0; n < 4; n++) {
            f4 w = (f4){b2c.x, b2c.y, b2c.z, b2c.w};
            w = __builtin_amdgcn_mfma_f32_16x16x32_bf16(a0, hb[n][0], w, 0, 0, 0);
            w = __builtin_amdgcn_mfma_f32_16x16x32_bf16(a1, hb[n][1], w, 0, 0, 0);
            w = __builtin_amdgcn_mfma_f32_16x16x32_bf16(a2, hb[n][2], w, 0, 0, 0);
            w = __builtin_amdgcn_mfma_f32_16x16x32_bf16(a3, hb[n][3], w, 0, 0, 0);
            wf[n] = w;
        }

        // contraction (all partials in registers; u is compile-time-simple per range)
        if (k4 < 64) {                        // A: u = k4, out0 cols [16w,16w+16)
#pragma unroll
            for (int n = 0; n < 4; n++) {
                float sv = sh0n[n] * sT[k4][n * 16 + el];
                acc0[n] += sv * wf[n];
            }
        } else if (k4 < 80) {                 // B: u = 4*(k4-64)+wave (cross-wave partial)
            int u = (k4 - 64) * 4 + wave;
#pragma unroll
            for (int n = 0; n < 4; n++) accB[n] += sT[u][n * 16 + el] * wf[n];
        } else if (k4 < 84) {                 // C: u = 4*(k4-80)+wave (cross-wave partial)
            int u = (k4 - 80) * 4 + wave;
#pragma unroll
            for (int n = 0; n < 4; n++) {
                int e = n * 16 + el;
#pragma unroll
                for (int i = 0; i < 3; i++) accC[i][n] += vT[i][u][e] * wf[n];
            }
        } else {                              // D: u = k4-84, out0 cols [16w,16w+16)
#pragma unroll
            for (int n = 0; n < 4; n++) acc0[n] += pT[k4 - 84][n * 16 + el] * wf[n];
        }
        if (k4 < 99) b2c = b2n;
    }

    __syncthreads();   // loop reads of stage/sT/vT/pT done -> repurpose for epilogue

    // zero epilogue reduction buffers (stage region) + stage out0 into sT (now dead)
    for (int i = tid; i < 64 * 66; i += 256) ((float*)&ovl.ep)[i] = 0.f;
#pragma unroll
    for (int n = 0; n < 4; n++) {
        int e = n * 16 + el;
#pragma unroll
        for (int r = 0; r < 4; r++)
            sT[e][wave * 16 + q4 * 4 + r] = N0_CONST * acc0[n][r];
    }
    __syncthreads();

    // cross-wave reductions for B and C partials
#pragma unroll
    for (int n = 0; n < 4; n++) {
        int e = n * 16 + el;
#pragma unroll
        for (int r = 0; r < 4; r++) {
            unsafeAtomicAdd(&ovl.ep.redB[q4 * 4 + r][e], accB[n][r]);
#pragma unroll
            for (int i = 0; i < 3; i++)
                unsafeAtomicAdd(&ovl.ep.accC[i * 16 + q4 * 4 + r][e], accC[i][n][r]);
        }
    }
    __syncthreads();

    // single coalesced 28KB nontemporal store of tp[e0..e0+64)[0..112)
    float* tpe = tp + (size_t)e0 * 112;
    for (int idx = tid; idx < 64 * 112; idx += 256) {
        int e = idx / 112;
        int c = idx - e * 112;
        float val;
        if (c < 64) {
            val = sT[e][c];
        } else {
            int cr = c - 64;
            int wp = cr / 3;
            int i = cr - wp * 3;
            val = N0_CONST * (ovl.ep.redB[wp][e] * sh1_s[i][e] + ovl.ep.accC[i * 16 + wp][e] * sh0_s[e]);
        }
        __builtin_nontemporal_store(val, &tpe[idx]);
    }
}

// Per-node segment mean over CSR edge list + residual. Block = node, thread = col.
__global__ __launch_bounds__(128) void k_red(const float* __restrict__ tp,
                                             const int* __restrict__ ptr,
                                             const int* __restrict__ eids,
                                             const float* __restrict__ node_attr,
                                             float* __restrict__ out) {
    int n = blockIdx.x;
    int c = threadIdx.x;
    if (c >= 112) return;
    int a = ptr[n], b = ptr[n + 1];
    float s = 0.f;
    for (int i = a; i < b; i++) {
        int e = eids[i];
        s += tp[(size_t)e * 112 + c];
    }
    float d = fmaxf((float)(b - a), 1.f);
    out[n * 112 + c] = s / d + node_attr[n * 112 + c];
}

extern "C" void kernel_launch(void* const* d_in, const int* in_sizes, int n_in,
                              void* d_out, int out_size, void* d_ws, size_t ws_size,
                              hipStream_t stream) {
    const float* node_attr  = (const float*)d_in[0];
    const int*   edge_index = (const int*)d_in[1];
    const float* edge_attr  = (const float*)d_in[2];
    const float* edge_sh    = (const float*)d_in[3];
    const float* W1         = (const float*)d_in[6];
    const float* b1         = (const float*)d_in[7];
    const float* W2         = (const float*)d_in[8];
    const float* b2         = (const float*)d_in[9];
    float* out = (float*)d_out;

    char* ws = (char*)d_ws;
    u16*   w2s    = (u16*)ws;                     // 6400*128*2  = 1,638,400
    u16*   w1t    = (u16*)(ws + 1638400);         // 128*128*2   =    32,768
    u16*   hgl    = (u16*)(ws + 1671168);         // 32768*128*2 = 8,388,608
    float* tp     = (float*)(ws + 10059776);      // 32768*112*4 = 14,680,064
    int*   deg    = (int*)(ws + 24739840);        // 4096*4
    int*   ptr    = (int*)(ws + 24756224);        // 4097*4
    int*   cursor = (int*)(ws + 24772624);        // 4096*4
    int*   eids   = (int*)(ws + 24789024);        // 32768*4

    hipMemsetAsync(deg, 0, 16384, stream);
    k_prep<<<544, 256, 0, stream>>>(W2, W1, edge_index, w2s, w1t, deg);
    k_scan<<<1, 64, 0, stream>>>(deg, ptr, cursor);
    k_h<<<512, 256, 0, stream>>>(edge_attr, w1t, b1, edge_index, cursor, eids, hgl);
    k_main<<<512, 256, 0, stream>>>(w2s, hgl, b2, node_attr, edge_index, edge_sh, tp);
    k_red<<<4096, 128, 0, stream>>>(tp, ptr, eids, node_attr, out);
}

// Round 9
// 245.349 us; speedup vs baseline: 1.0922x; 1.0922x over previous
//
#include <hip/hip_runtime.h>

typedef unsigned short u16;
typedef __bf16 bf8 __attribute__((ext_vector_type(8)));
typedef float f4 __attribute__((ext_vector_type(4)));

#define E_EDGES 32768
#define N_NODES 4096
// col layout of w (WNUM=6400): A[u<64][w<64] @0, B[u<64][w<16] @4096, C[u<16][w<16] @5120, D[u<16][w<64] @5376
// tile mt covers cols [mt*16,mt*16+16). 512-thread blocks: wave quad h=wave>>2 takes m-parity half,
// wave&3 = n-tile (16 edges). Group p4 covers periods 4p4..4p4+3; wave's tile mt = 8*p4 + j + 4*h.
// Ranges by p4: A p4<32 (u=2p4+h, colblk j), B 32..39 (u=8p4-256+j+4h), C 40..41 (u=8p4-320+j+4h),
// D 42..49 (u=2p4-84+h, colblk j).
#define N0_CONST 0.1118033988749895f       // sqrt(1/80); also equals N1*INV_SQRT3
#define INV_SQRT3_CONST 0.5773502691896258f

__device__ __forceinline__ u16 f2bf(float f) {
    unsigned u = __float_as_uint(f);
    u += 0x7FFFu + ((u >> 16) & 1u);   // RNE
    return (u16)(u >> 16);
}

__device__ __forceinline__ void gld16(const u16* g, u16* l) {
    __builtin_amdgcn_global_load_lds((const __attribute__((address_space(1))) void*)g,
                                     (__attribute__((address_space(3))) void*)l, 16, 0, 0);
}

// Weight prep + src-degree histogram, one launch:
//  blocks 0..399:   w2s fragment-order swizzle (tile = 4KB contiguous)
//  blocks 400..415: w1t[c*128+k] = bf16(W1[k*128+c])
//  blocks 416..543: deg histogram over edge src (deg pre-zeroed by memsetAsync)
__global__ __launch_bounds__(256) void k_prep(const float* __restrict__ W2, const float* __restrict__ W1,
                                              const int* __restrict__ edge_index,
                                              u16* __restrict__ w2s, u16* __restrict__ w1t,
                                              int* __restrict__ deg) {
    int b = blockIdx.x;
    int tid = threadIdx.x;
    if (b < 400) {
        int ks = tid >> 6, l = tid & 63;
        int el = l & 15, q4 = l >> 4;
        int c = b * 16 + el;
        u16 tmp[8];
#pragma unroll
        for (int j = 0; j < 8; j++) {
            int k = ks * 32 + q4 * 8 + j;
            tmp[j] = f2bf(W2[(size_t)k * 6400 + c]);
        }
        *(uint4*)(w2s + b * 2048 + ks * 512 + l * 8) = *(uint4*)tmp;
    } else if (b < 416) {
        int t = (b - 400) * 256 + tid;
#pragma unroll
        for (int i = 0; i < 4; i++) {
            int idx = t * 4 + i;                // idx = c*128 + k
            int c = idx >> 7, k = idx & 127;
            w1t[idx] = f2bf(W1[k * 128 + c]);
        }
    } else {
        int t = (b - 416) * 256 + tid;          // 128 blocks * 256 = 32768 = E
        atomicAdd(&deg[edge_index[t]], 1);
    }
}

// Exclusive scan of deg[4096] -> ptr[0..4096] and cursor copy. 1 block, 64 threads.
__global__ void k_scan(const int* __restrict__ deg, int* __restrict__ ptr, int* __restrict__ cursor) {
    int t = threadIdx.x;           // 0..63
    int base = t * 64;
    int s = 0;
    for (int i = 0; i < 64; i++) s += deg[base + i];
    int x = s;
#pragma unroll
    for (int d = 1; d < 64; d <<= 1) {
        int y = __shfl_up(x, d, 64);
        if (t >= d) x += y;
    }
    int run = x - s;               // exclusive prefix
    for (int i = 0; i < 64; i++) {
        ptr[base + i] = run;
        cursor[base + i] = run;
        run += deg[base + i];
    }
    if (t == 63) ptr[4096] = run;
}

// h = relu(edge_attr @ W1 + b1), stored bf16 [E][128]; also fills CSR edge-id list via cursor
__global__ __launch_bounds__(256) void k_h(const float* __restrict__ ea,
                                           const u16* __restrict__ w1t,
                                           const float* __restrict__ b1,
                                           const int* __restrict__ edge_index,
                                           int* __restrict__ cursor,
                                           int* __restrict__ eids,
                                           u16* __restrict__ h) {
    __shared__ alignas(16) u16 ea_s[64][128];
    int tid = threadIdx.x;
    int e0 = blockIdx.x * 64;
    if (tid < 64) {                // CSR fill for this block's 64 edges
        int ge = e0 + tid;
        int s = edge_index[ge];
        int pos = atomicAdd(&cursor[s], 1);
        eids[pos] = ge;
    }
    {
        int e = tid >> 2, q = tid & 3;
        const float4* src = (const float4*)(ea + (size_t)(e0 + e) * 128 + q * 32);
#pragma unroll
        for (int i = 0; i < 8; i++) {
            float4 f = src[i];
            int c = q * 32 + i * 4;
            ea_s[e][c + 0] = f2bf(f.x); ea_s[e][c + 1] = f2bf(f.y);
            ea_s[e][c + 2] = f2bf(f.z); ea_s[e][c + 3] = f2bf(f.w);
        }
    }
    __syncthreads();
    int lane = tid & 63, wave = tid >> 6;
    int el = lane & 15, q4 = lane >> 4;
    f4 acc[4][2];
#pragma unroll
    for (int m = 0; m < 4; m++)
#pragma unroll
        for (int nt = 0; nt < 2; nt++) acc[m][nt] = (f4){0.f, 0.f, 0.f, 0.f};
#pragma unroll
    for (int ks = 0; ks < 4; ks++) {
        bf8 a[4], b[2];
#pragma unroll
        for (int m = 0; m < 4; m++) a[m] = *(const bf8*)&ea_s[m * 16 + el][ks * 32 + q4 * 8];
#pragma unroll
        for (int nt = 0; nt < 2; nt++) {
            int n = wave * 32 + nt * 16 + el;
            b[nt] = *(const bf8*)(w1t + n * 128 + ks * 32 + q4 * 8);
        }
#pragma unroll
        for (int m = 0; m < 4; m++)
#pragma unroll
            for (int nt = 0; nt < 2; nt++)
                acc[m][nt] = __builtin_amdgcn_mfma_f32_16x16x32_bf16(a[m], b[nt], acc[m][nt], 0, 0, 0);
    }
#pragma unroll
    for (int m = 0; m < 4; m++)
#pragma unroll
        for (int nt = 0; nt < 2; nt++) {
            int n = wave * 32 + nt * 16 + el;
            float bias = b1[n];
#pragma unroll
            for (int r = 0; r < 4; r++) {
                int e = e0 + m * 16 + q4 * 4 + r;
                float v = fmaxf(acc[m][nt][r] + bias, 0.f);
                h[(size_t)e * 128 + n] = f2bf(v);
            }
        }
}

// Fused: w = h@W2+b2 tile-by-tile -> contraction -> tp[E][112].
// 512 threads = 8 waves = 2 wave-quads; quad h processes m-parity half h. Per period:
// stage 2 tiles (8KB, 1 gld16/thread), wave consumes its half's tile (4 ds_read_b128 + 4 MFMA).
// Halves merge in 2 phased plain-LDS writes (no atomics). 16 waves/CU at 51.7KB LDS.
__global__ __launch_bounds__(512, 4) void k_main(const u16* __restrict__ w2s,
                                                 const u16* __restrict__ hgl,
                                                 const float* __restrict__ b2,
                                                 const float* __restrict__ node_attr,
                                                 const int* __restrict__ edge_index,
                                                 const float* __restrict__ edge_sh,
                                                 float* __restrict__ tp) {
    __shared__ union {
        u16 h[64][128];                                        // 16 KB (prologue)
        u16 stage[2][2][2048];                                 // 16 KB (loop: [buf][half][tile])
        struct { float redB[16][66]; float accC[48][66]; } ep; // 16.9 KB (epilogue)
    } ovl;
    __shared__ float sT[64][65];              // s[u][e]; epilogue: out0[e][c]
    __shared__ float vT[3][16][66];           // v[i][u][e]
    __shared__ float pT[16][66];              // INV_SQRT3*(v.sh1)[u][e]
    __shared__ float sh0_s[64];
    __shared__ float sh1_s[3][64];
    __shared__ int dst_s[64];

    int tid = threadIdx.x;
    int e0 = blockIdx.x * 64;

    // phase 1: edge meta
    if (tid < 64) {
        int ge = e0 + tid;
        dst_s[tid] = edge_index[E_EDGES + ge];
        float4 sh = *(const float4*)(edge_sh + (size_t)ge * 4);
        sh0_s[tid] = sh.x; sh1_s[0][tid] = sh.y; sh1_s[1][tid] = sh.z; sh1_s[2][tid] = sh.w;
    }
    __syncthreads();

    // phase 2: tid<256 -> node features (transposed into LDS); tid>=256 -> h tile into ovl.h
    if (tid < 256) {
        int e = tid >> 2, q = tid & 3;
        int dst = dst_s[e];
        const float* xp = node_attr + (size_t)dst * 112;
#pragma unroll
        for (int i = 0; i < 4; i++) {
            float4 f = *(const float4*)(xp + q * 16 + i * 4);
            int u = q * 16 + i * 4;
            sT[u + 0][e] = f.x; sT[u + 1][e] = f.y; sT[u + 2][e] = f.z; sT[u + 3][e] = f.w;
        }
        float vv[12];
#pragma unroll
        for (int i = 0; i < 3; i++) {
            float4 f = *(const float4*)(xp + 64 + q * 12 + i * 4);
            vv[i * 4 + 0] = f.x; vv[i * 4 + 1] = f.y; vv[i * 4 + 2] = f.z; vv[i * 4 + 3] = f.w;
        }
        float s1x = sh1_s[0][e], s1y = sh1_s[1][e], s1z = sh1_s[2][e];
#pragma unroll
        for (int u = 0; u < 4; u++) {
            float xa = vv[u * 3 + 0], xb = vv[u * 3 + 1], xc = vv[u * 3 + 2];
            int uu = q * 4 + u;
            vT[0][uu][e] = xa; vT[1][uu][e] = xb; vT[2][uu][e] = xc;
            pT[uu][e] = INV_SQRT3_CONST * (xa * s1x + xb * s1y + xc * s1z);
        }
    } else {
        int t = tid - 256;
        int e = t >> 2, q = t & 3;
        const uint4* hsrc = (const uint4*)(hgl + (size_t)(e0 + e) * 128) + q * 4;
        uint4* hdst = (uint4*)(&ovl.h[e][q * 32]);
#pragma unroll
        for (int i = 0; i < 4; i++) hdst[i] = hsrc[i];
    }
    __syncthreads();

    int lane = tid & 63, wave = tid >> 6;
    int el = lane & 15, q4 = lane >> 4;
    int hh = __builtin_amdgcn_readfirstlane(wave >> 2);   // m-parity half (scalar)
    int eln = (wave & 3) * 16 + el;                        // this wave's edge for this lane

    // B-fragments: wave owns n-tile = its 16 edges -> 4 bf8 (16 VGPRs)
    bf8 hb[4];
#pragma unroll
    for (int ks = 0; ks < 4; ks++)
        hb[ks] = *(const bf8*)&ovl.h[eln][ks * 32 + q4 * 8];
    float sh0n = sh0_s[eln];
    __syncthreads();   // h region free -> becomes stage buffers

    f4 acc0[4], accB, accC[3];
#pragma unroll
    for (int j = 0; j < 4; j++) acc0[j] = (f4){0.f, 0.f, 0.f, 0.f};
    accB = (f4){0.f, 0.f, 0.f, 0.f};
#pragma unroll
    for (int i = 0; i < 3; i++) accC[i] = (f4){0.f, 0.f, 0.f, 0.f};

    // preload period 0: even tile 0 -> stage[0][0], odd tile 4 -> stage[0][1]
    {
        int g = tid >> 8, c = tid & 255;
        gld16(w2s + (size_t)(4 * g) * 2048 + c * 8, &ovl.stage[0][g][c * 8]);
    }

    for (int p4 = 0; p4 < 50; p4++) {
        // hoisted per-group scale (one ds_read per group instead of 4)
        float sA = 0.f, pD = 0.f;
        if (p4 < 32) sA = sh0n * sT[2 * p4 + hh][eln];
        else if (p4 >= 42) pD = pT[2 * p4 - 84 + hh][eln];
#pragma unroll
        for (int j = 0; j < 4; j++) {
            int p = p4 * 4 + j;
            __syncthreads();                   // buf[p&1] staged; prior period's reads done
            int mt = 8 * p4 + j + 4 * hh;
            float4 b2v = *(const float4*)(b2 + (size_t)mt * 16 + q4 * 4);   // oldest vm op
            if (p < 199) {                     // prefetch period p+1 -> other buffer
                int pn = p + 1;
                int g = tid >> 8, c = tid & 255;
                int mtg = 8 * (pn >> 2) + (pn & 3) + 4 * g;
                gld16(w2s + (size_t)mtg * 2048 + c * 8, &ovl.stage[pn & 1][g][c * 8]);
            }
            const u16* sp = &ovl.stage[p & 1][hh][lane * 8];
            bf8 a0 = *(const bf8*)(sp);
            bf8 a1 = *(const bf8*)(sp + 512);
            bf8 a2 = *(const bf8*)(sp + 1024);
            bf8 a3 = *(const bf8*)(sp + 1536);
            f4 wv = (f4){b2v.x, b2v.y, b2v.z, b2v.w};
            wv = __builtin_amdgcn_mfma_f32_16x16x32_bf16(a0, hb[0], wv, 0, 0, 0);
            wv = __builtin_amdgcn_mfma_f32_16x16x32_bf16(a1, hb[1], wv, 0, 0, 0);
            wv = __builtin_amdgcn_mfma_f32_16x16x32_bf16(a2, hb[2], wv, 0, 0, 0);
            wv = __builtin_amdgcn_mfma_f32_16x16x32_bf16(a3, hb[3], wv, 0, 0, 0);

            if (p4 < 32) {                     // A: colblk j
                acc0[j] += sA * wv;
            } else if (p4 < 40) {              // B
                accB += sT[8 * p4 - 256 + j + 4 * hh][eln] * wv;
            } else if (p4 < 42) {              // C
                int u = 8 * p4 - 320 + j + 4 * hh;
#pragma unroll
                for (int i = 0; i < 3; i++) accC[i] += vT[i][u][eln] * wv;
            } else {                           // D: colblk j
                acc0[j] += pD * wv;
            }
        }
    }

    __syncthreads();   // all loop reads of stage/sT/vT/pT done -> epilogue overlays

    // phased half-merge (no atomics): h=0 writes, barrier, h=1 adds
    if (hh == 0) {
#pragma unroll
        for (int j = 0; j < 4; j++)
#pragma unroll
            for (int r = 0; r < 4; r++)
                sT[eln][j * 16 + q4 * 4 + r] = acc0[j][r];
#pragma unroll
        for (int r = 0; r < 4; r++) {
            ovl.ep.redB[q4 * 4 + r][eln] = accB[r];
#pragma unroll
            for (int i = 0; i < 3; i++)
                ovl.ep.accC[i * 16 + q4 * 4 + r][eln] = accC[i][r];
        }
    }
    __syncthreads();
    if (hh == 1) {
#pragma unroll
        for (int j = 0; j < 4; j++)
#pragma unroll
            for (int r = 0; r < 4; r++)
                sT[eln][j * 16 + q4 * 4 + r] += acc0[j][r];
#pragma unroll
        for (int r = 0; r < 4; r++) {
            ovl.ep.redB[q4 * 4 + r][eln] += accB[r];
#pragma unroll
            for (int i = 0; i < 3; i++)
                ovl.ep.accC[i * 16 + q4 * 4 + r][eln] += accC[i][r];
        }
    }
    __syncthreads();

    // single coalesced 28KB nontemporal store of tp[e0..e0+64)[0..112)
    float* tpe = tp + (size_t)e0 * 112;
    for (int idx = tid; idx < 64 * 112; idx += 512) {
        int e = idx / 112;
        int c = idx - e * 112;
        float val;
        if (c < 64) {
            val = N0_CONST * sT[e][c];
        } else {
            int cr = c - 64;
            int wp = cr / 3;
            int i = cr - wp * 3;
            val = N0_CONST * (ovl.ep.redB[wp][e] * sh1_s[i][e] + ovl.ep.accC[i * 16 + wp][e] * sh0_s[e]);
        }
        __builtin_nontemporal_store(val, &tpe[idx]);
    }
}

// Per-node segment mean over CSR edge list + residual. Block = node, thread = col.
__global__ __launch_bounds__(128) void k_red(const float* __restrict__ tp,
                                             const int* __restrict__ ptr,
                                             const int* __restrict__ eids,
                                             const float* __restrict__ node_attr,
                                             float* __restrict__ out) {
    int n = blockIdx.x;
    int c = threadIdx.x;
    if (c >= 112) return;
    int a = ptr[n], b = ptr[n + 1];
    float s = 0.f;
    for (int i = a; i < b; i++) {
        int e = eids[i];
        s += tp[(size_t)e * 112 + c];
    }
    float d = fmaxf((float)(b - a), 1.f);
    out[n * 112 + c] = s / d + node_attr[n * 112 + c];
}

extern "C" void kernel_launch(void* const* d_in, const int* in_sizes, int n_in,
                              void* d_out, int out_size, void* d_ws, size_t ws_size,
                              hipStream_t stream) {
    const float* node_attr  = (const float*)d_in[0];
    const int*   edge_index = (const int*)d_in[1];
    const float* edge_attr  = (const float*)d_in[2];
    const float* edge_sh    = (const float*)d_in[3];
    const float* W1         = (const float*)d_in[6];
    const float* b1         = (const float*)d_in[7];
    const float* W2         = (const float*)d_in[8];
    const float* b2         = (const float*)d_in[9];
    float* out = (float*)d_out;

    char* ws = (char*)d_ws;
    u16*   w2s    = (u16*)ws;                     // 6400*128*2  = 1,638,400
    u16*   w1t    = (u16*)(ws + 1638400);         // 128*128*2   =    32,768
    u16*   hgl    = (u16*)(ws + 1671168);         // 32768*128*2 = 8,388,608
    float* tp     = (float*)(ws + 10059776);      // 32768*112*4 = 14,680,064
    int*   deg    = (int*)(ws + 24739840);        // 4096*4
    int*   ptr    = (int*)(ws + 24756224);        // 4097*4
    int*   cursor = (int*)(ws + 24772624);        // 4096*4
    int*   eids   = (int*)(ws + 24789024);        // 32768*4

    hipMemsetAsync(deg, 0, 16384, stream);
    k_prep<<<544, 256, 0, stream>>>(W2, W1, edge_index, w2s, w1t, deg);
    k_scan<<<1, 64, 0, stream>>>(deg, ptr, cursor);
    k_h<<<512, 256, 0, stream>>>(edge_attr, w1t, b1, edge_index, cursor, eids, hgl);
    k_main<<<512, 512, 0, stream>>>(w2s, hgl, b2, node_attr, edge_index, edge_sh, tp);
    k_red<<<4096, 128, 0, stream>>>(tp, ptr, eids, node_attr, out);
}